// Round 2
// baseline (151.418 us; speedup 1.0000x reference)
//
#include <hip/hip_runtime.h>
#include <math.h>

#define B_BATCH 64
#define N_PTS   65536
#define BPB     64                  // blocks per batch
#define THREADS 256
#define CHUNK   (N_PTS / BPB)       // 1024 points per block = 256 thr * 4

// ---------------------------------------------------------------------------
// Kernel 1: per-batch partial sums. Each thread handles exactly one float4
// group from each of the 7 streams (w, s0..2, t0..2) -> 7 independent loads
// in flight, no loop, no vmcnt(0) round-trip. Per-block 16 partial sums are
// written to ws (no atomics, no zero-init kernel needed).
//   part[(b*BPB+blk)*16 + k], k: 0=sum w, 1..3=sum w*s, 4..6=sum w*t,
//                                7..15=sum w*s_i*t_j (row-major)
// ---------------------------------------------------------------------------
__global__ __launch_bounds__(THREADS) void partial_sums(
        const float* __restrict__ src, const float* __restrict__ tgt,
        const float* __restrict__ w,  float* __restrict__ part) {
    const int b   = blockIdx.x / BPB;
    const int blk = blockIdx.x % BPB;
    const int n0  = blk * CHUNK;
    const int t   = threadIdx.x;

    const float4* wp = (const float4*)(w   + (size_t)b * N_PTS          + n0);
    const float4* s0 = (const float4*)(src + ((size_t)b*3 + 0) * N_PTS + n0);
    const float4* s1 = (const float4*)(src + ((size_t)b*3 + 1) * N_PTS + n0);
    const float4* s2 = (const float4*)(src + ((size_t)b*3 + 2) * N_PTS + n0);
    const float4* t0 = (const float4*)(tgt + ((size_t)b*3 + 0) * N_PTS + n0);
    const float4* t1 = (const float4*)(tgt + ((size_t)b*3 + 1) * N_PTS + n0);
    const float4* t2 = (const float4*)(tgt + ((size_t)b*3 + 2) * N_PTS + n0);

    // 7 independent 16B loads, all issued before any use
    float4 wv = wp[t];
    float4 x0 = s0[t], x1 = s1[t], x2 = s2[t];
    float4 y0 = t0[t], y1 = t1[t], y2 = t2[t];

    float a[16];
#pragma unroll
    for (int k = 0; k < 16; ++k) a[k] = 0.0f;

#define ACC(C) { \
    float ww = wv.C; \
    float ws0 = ww * x0.C, ws1 = ww * x1.C, ws2 = ww * x2.C; \
    float yy0 = y0.C, yy1 = y1.C, yy2 = y2.C; \
    a[0]  += ww; \
    a[1]  += ws0;        a[2]  += ws1;        a[3]  += ws2; \
    a[4]  += ww * yy0;   a[5]  += ww * yy1;   a[6]  += ww * yy2; \
    a[7]  += ws0 * yy0;  a[8]  += ws0 * yy1;  a[9]  += ws0 * yy2; \
    a[10] += ws1 * yy0;  a[11] += ws1 * yy1;  a[12] += ws1 * yy2; \
    a[13] += ws2 * yy0;  a[14] += ws2 * yy1;  a[15] += ws2 * yy2; }
    ACC(x) ACC(y) ACC(z) ACC(w)
#undef ACC

    // block reduction: wave64 shuffle tree, then LDS across the 4 waves
    const int lane = t & 63;
    const int wave = t >> 6;
    __shared__ float lds[4][16];
#pragma unroll
    for (int k = 0; k < 16; ++k) {
        float v = a[k];
        v += __shfl_down(v, 32);
        v += __shfl_down(v, 16);
        v += __shfl_down(v, 8);
        v += __shfl_down(v, 4);
        v += __shfl_down(v, 2);
        v += __shfl_down(v, 1);
        if (lane == 0) lds[wave][k] = v;
    }
    __syncthreads();
    if (t < 16) {
        float v = lds[0][t] + lds[1][t] + lds[2][t] + lds[3][t];
        part[(size_t)(b * BPB + blk) * 16 + t] = v;   // plain store, no atomic
    }
}

// ---------------------------------------------------------------------------
// Kernel 2: one block per batch. 64 lanes each load one partial (16 floats),
// shuffle-reduce across the wave, lane 0 runs fp32 Jacobi Kabsch.
// ---------------------------------------------------------------------------
__global__ __launch_bounds__(64) void finalize(
        const float* __restrict__ part, float* __restrict__ out) {
    const int b = blockIdx.x;
    const int l = threadIdx.x;      // 0..63

    const float4* p = (const float4*)(part + (size_t)(b * BPB + l) * 16);
    float4 q0 = p[0], q1 = p[1], q2 = p[2], q3 = p[3];
    float a[16] = {q0.x,q0.y,q0.z,q0.w, q1.x,q1.y,q1.z,q1.w,
                   q2.x,q2.y,q2.z,q2.w, q3.x,q3.y,q3.z,q3.w};
#pragma unroll
    for (int k = 0; k < 16; ++k) {
        float v = a[k];
        v += __shfl_down(v, 32);
        v += __shfl_down(v, 16);
        v += __shfl_down(v, 8);
        v += __shfl_down(v, 4);
        v += __shfl_down(v, 2);
        v += __shfl_down(v, 1);
        a[k] = v;                   // valid on lane 0 only
    }
    if (l != 0) return;

    float W = a[0];
    float A[3]  = {a[1], a[2], a[3]};
    float Bv[3] = {a[4], a[5], a[6]};
    float H[3][3];
#pragma unroll
    for (int i = 0; i < 3; ++i)
#pragma unroll
        for (int j = 0; j < 3; ++j)
            H[i][j] = a[7 + i*3 + j] + (W - 2.0f) * A[i] * Bv[j];

    // scale-normalize H (R is scale-invariant)
    float fn = 0.0f;
    for (int i = 0; i < 3; ++i) for (int j = 0; j < 3; ++j) fn += H[i][j]*H[i][j];
    fn = sqrtf(fn);
    float inv = (fn > 1e-30f) ? 1.0f/fn : 1.0f;
    float h[3][3];
    for (int i = 0; i < 3; ++i) for (int j = 0; j < 3; ++j) h[i][j] = H[i][j]*inv;

    // M = h^T h
    float M[3][3];
    for (int i = 0; i < 3; ++i)
        for (int j = 0; j < 3; ++j) {
            float s = 0.0f;
            for (int k = 0; k < 3; ++k) s += h[k][i] * h[k][j];
            M[i][j] = s;
        }

    // cyclic Jacobi: M = V diag(e) V^T
    float V[3][3] = {{1,0,0},{0,1,0},{0,0,1}};
    const int PAIRS[3][2] = {{0,1},{0,2},{1,2}};
    for (int sweep = 0; sweep < 12; ++sweep) {
        float off = M[0][1]*M[0][1] + M[0][2]*M[0][2] + M[1][2]*M[1][2];
        if (off < 1e-14f) break;
        for (int pp = 0; pp < 3; ++pp) {
            const int pq = PAIRS[pp][0], qq = PAIRS[pp][1];
            float apq = M[pq][qq];
            if (fabsf(apq) < 1e-30f) continue;
            float tau = (M[qq][qq] - M[pq][pq]) / (2.0f * apq);
            float t = (tau >= 0.0f ? 1.0f : -1.0f) / (fabsf(tau) + sqrtf(1.0f + tau*tau));
            float c = 1.0f / sqrtf(1.0f + t*t), s = t * c;
            for (int k = 0; k < 3; ++k) {
                float mkp = M[k][pq], mkq = M[k][qq];
                M[k][pq] = c*mkp - s*mkq;
                M[k][qq] = s*mkp + c*mkq;
            }
            for (int k = 0; k < 3; ++k) {
                float mpk = M[pq][k], mqk = M[qq][k];
                M[pq][k] = c*mpk - s*mqk;
                M[qq][k] = s*mpk + c*mqk;
            }
            for (int k = 0; k < 3; ++k) {
                float vkp = V[k][pq], vkq = V[k][qq];
                V[k][pq] = c*vkp - s*vkq;
                V[k][qq] = s*vkp + c*vkq;
            }
        }
    }

    // sort eigenvalues descending -> permute V columns
    float e[3] = {M[0][0], M[1][1], M[2][2]};
    int idx[3] = {0, 1, 2};
    if (e[idx[0]] < e[idx[1]]) { int t_ = idx[0]; idx[0] = idx[1]; idx[1] = t_; }
    if (e[idx[0]] < e[idx[2]]) { int t_ = idx[0]; idx[0] = idx[2]; idx[2] = t_; }
    if (e[idx[1]] < e[idx[2]]) { int t_ = idx[1]; idx[1] = idx[2]; idx[2] = t_; }
    float Vc[3][3];
    for (int i = 0; i < 3; ++i)
        for (int k = 0; k < 3; ++k) Vc[i][k] = V[i][idx[k]];

    // left singular vectors: u_k = h*v_k / |h*v_k|; u3 = u1 x u2
    float u[3][3], hv[3][3];
    for (int k = 0; k < 3; ++k)
        for (int j = 0; j < 3; ++j) {
            float s = 0.0f;
            for (int m = 0; m < 3; ++m) s += h[j][m] * Vc[m][k];
            hv[k][j] = s;
        }
    float n1 = sqrtf(hv[0][0]*hv[0][0] + hv[0][1]*hv[0][1] + hv[0][2]*hv[0][2]);
    float in1 = (n1 > 1e-20f) ? 1.0f/n1 : 0.0f;
    for (int j = 0; j < 3; ++j) u[0][j] = hv[0][j] * in1;
    if (in1 == 0.0f) { u[0][0] = 1.0f; u[0][1] = 0.0f; u[0][2] = 0.0f; }
    float d12 = u[0][0]*hv[1][0] + u[0][1]*hv[1][1] + u[0][2]*hv[1][2];
    float w2[3];
    for (int j = 0; j < 3; ++j) w2[j] = hv[1][j] - d12 * u[0][j];
    float n2 = sqrtf(w2[0]*w2[0] + w2[1]*w2[1] + w2[2]*w2[2]);
    if (n2 > 1e-20f) {
        for (int j = 0; j < 3; ++j) u[1][j] = w2[j] / n2;
    } else {
        float ax = fabsf(u[0][0]), ay = fabsf(u[0][1]), az = fabsf(u[0][2]);
        float t2[3];
        if (ax <= ay && ax <= az)      { t2[0]=0; t2[1]=-u[0][2]; t2[2]=u[0][1]; }
        else if (ay <= az)             { t2[0]=-u[0][2]; t2[1]=0; t2[2]=u[0][0]; }
        else                           { t2[0]=-u[0][1]; t2[1]=u[0][0]; t2[2]=0; }
        float nt = sqrtf(t2[0]*t2[0] + t2[1]*t2[1] + t2[2]*t2[2]);
        for (int j = 0; j < 3; ++j) u[1][j] = t2[j] / nt;
    }
    u[2][0] = u[0][1]*u[1][2] - u[0][2]*u[1][1];
    u[2][1] = u[0][2]*u[1][0] - u[0][0]*u[1][2];
    u[2][2] = u[0][0]*u[1][1] - u[0][1]*u[1][0];

    // R0 = V U^T; det fix flips V's 3rd column
    float R[3][3];
    for (int i = 0; i < 3; ++i)
        for (int j = 0; j < 3; ++j) {
            float s = 0.0f;
            for (int k = 0; k < 3; ++k) s += Vc[i][k] * u[k][j];
            R[i][j] = s;
        }
    float det = R[0][0]*(R[1][1]*R[2][2] - R[1][2]*R[2][1])
              - R[0][1]*(R[1][0]*R[2][2] - R[1][2]*R[2][0])
              + R[0][2]*(R[1][0]*R[2][1] - R[1][1]*R[2][0]);
    if (det < 0.0f)
        for (int i = 0; i < 3; ++i)
            for (int j = 0; j < 3; ++j)
                R[i][j] -= 2.0f * Vc[i][2] * u[2][j];

    float tv[3];
    for (int i = 0; i < 3; ++i)
        tv[i] = Bv[i] - (R[i][0]*A[0] + R[i][1]*A[1] + R[i][2]*A[2]);

    for (int i = 0; i < 3; ++i)
        for (int j = 0; j < 3; ++j)
            out[b*9 + i*3 + j] = R[i][j];
    for (int i = 0; i < 3; ++i)
        out[B_BATCH*9 + b*3 + i] = tv[i];
}

// ---------------------------------------------------------------------------
extern "C" void kernel_launch(void* const* d_in, const int* in_sizes, int n_in,
                              void* d_out, int out_size, void* d_ws, size_t ws_size,
                              hipStream_t stream) {
    const float* src = (const float*)d_in[0];
    const float* tgt = (const float*)d_in[1];
    const float* w   = (const float*)d_in[2];
    float* out  = (float*)d_out;
    float* part = (float*)d_ws;     // 64*64*16 floats = 256 KB

    partial_sums<<<B_BATCH * BPB, THREADS, 0, stream>>>(src, tgt, w, part);
    finalize<<<B_BATCH, 64, 0, stream>>>(part, out);
}

// Round 3
// 148.224 us; speedup vs baseline: 1.0215x; 1.0215x over previous
//
#include <hip/hip_runtime.h>
#include <math.h>

#define B_BATCH 64
#define N_PTS   65536
#define BPB     16                  // blocks per batch -> 1024 WGs (4/CU)
#define THREADS 256
#define CHUNK   (N_PTS / BPB)       // 4096 points per block
#define ITERS   (CHUNK / 4 / THREADS)   // 4 float4-iterations per thread

// ---------------------------------------------------------------------------
// Kernel 1: per-batch 16 weighted sums. Software-pipelined: each iteration's
// 7 float4 loads are issued before the previous iteration is consumed, so the
// memory queue never drains (R1/R2 burst-then-drain pinned BW at 2.8 TB/s).
//   part[(b*BPB+blk)*16 + k]: 0=sum w, 1..3=sum w*s, 4..6=sum w*t,
//                             7..15=sum w*s_i*t_j (row-major)
// ---------------------------------------------------------------------------
__global__ __launch_bounds__(THREADS) void partial_sums(
        const float* __restrict__ src, const float* __restrict__ tgt,
        const float* __restrict__ w,  float* __restrict__ part) {
    const int b   = blockIdx.x / BPB;
    const int blk = blockIdx.x % BPB;
    const int n0  = blk * CHUNK;
    const int t   = threadIdx.x;

    const float4* wp = (const float4*)(w   + (size_t)b * N_PTS          + n0);
    const float4* s0 = (const float4*)(src + ((size_t)b*3 + 0) * N_PTS + n0);
    const float4* s1 = (const float4*)(src + ((size_t)b*3 + 1) * N_PTS + n0);
    const float4* s2 = (const float4*)(src + ((size_t)b*3 + 2) * N_PTS + n0);
    const float4* t0 = (const float4*)(tgt + ((size_t)b*3 + 0) * N_PTS + n0);
    const float4* t1 = (const float4*)(tgt + ((size_t)b*3 + 1) * N_PTS + n0);
    const float4* t2 = (const float4*)(tgt + ((size_t)b*3 + 2) * N_PTS + n0);

    float a[16];
#pragma unroll
    for (int k = 0; k < 16; ++k) a[k] = 0.0f;

#define ACC4(WV, X0, X1, X2, Y0, Y1, Y2) \
    { ACC1(WV.x, X0.x, X1.x, X2.x, Y0.x, Y1.x, Y2.x) \
      ACC1(WV.y, X0.y, X1.y, X2.y, Y0.y, Y1.y, Y2.y) \
      ACC1(WV.z, X0.z, X1.z, X2.z, Y0.z, Y1.z, Y2.z) \
      ACC1(WV.w, X0.w, X1.w, X2.w, Y0.w, Y1.w, Y2.w) }
#define ACC1(WW, X0, X1, X2, Y0, Y1, Y2) { \
    float ww = WW; \
    float ws0 = ww * X0, ws1 = ww * X1, ws2 = ww * X2; \
    a[0]  += ww; \
    a[1]  += ws0;       a[2]  += ws1;       a[3]  += ws2; \
    a[4]  += ww * Y0;   a[5]  += ww * Y1;   a[6]  += ww * Y2; \
    a[7]  += ws0 * Y0;  a[8]  += ws0 * Y1;  a[9]  += ws0 * Y2; \
    a[10] += ws1 * Y0;  a[11] += ws1 * Y1;  a[12] += ws1 * Y2; \
    a[13] += ws2 * Y0;  a[14] += ws2 * Y1;  a[15] += ws2 * Y2; }

    // stage 0: issue first iteration's loads
    float4 wv = wp[t];
    float4 x0 = s0[t], x1 = s1[t], x2 = s2[t];
    float4 y0 = t0[t], y1 = t1[t], y2 = t2[t];

#pragma unroll
    for (int it = 0; it < ITERS - 1; ++it) {
        const int nx = t + (it + 1) * THREADS;
        // issue next iteration's 7 loads BEFORE consuming current
        float4 wv2 = wp[nx];
        float4 x0b = s0[nx], x1b = s1[nx], x2b = s2[nx];
        float4 y0b = t0[nx], y1b = t1[nx], y2b = t2[nx];
        ACC4(wv, x0, x1, x2, y0, y1, y2)
        wv = wv2; x0 = x0b; x1 = x1b; x2 = x2b;
        y0 = y0b; y1 = y1b; y2 = y2b;
    }
    ACC4(wv, x0, x1, x2, y0, y1, y2)
#undef ACC1
#undef ACC4

    // block reduction: wave64 shuffle tree, then LDS across the 4 waves
    const int lane = t & 63;
    const int wave = t >> 6;
    __shared__ float lds[4][16];
#pragma unroll
    for (int k = 0; k < 16; ++k) {
        float v = a[k];
        v += __shfl_down(v, 32);
        v += __shfl_down(v, 16);
        v += __shfl_down(v, 8);
        v += __shfl_down(v, 4);
        v += __shfl_down(v, 2);
        v += __shfl_down(v, 1);
        if (lane == 0) lds[wave][k] = v;
    }
    __syncthreads();
    if (t < 16) {
        float v = lds[0][t] + lds[1][t] + lds[2][t] + lds[3][t];
        part[(size_t)(b * BPB + blk) * 16 + t] = v;
    }
}

// ---------------------------------------------------------------------------
// Kernel 2: one block per batch. Lanes 0..BPB-1 load one partial each (16
// floats), shuffle-reduce across the wave, lane 0 runs fp32 Jacobi Kabsch.
// ---------------------------------------------------------------------------
__global__ __launch_bounds__(64) void finalize(
        const float* __restrict__ part, float* __restrict__ out) {
    const int b = blockIdx.x;
    const int l = threadIdx.x;      // 0..63

    float a[16];
    if (l < BPB) {
        const float4* p = (const float4*)(part + (size_t)(b * BPB + l) * 16);
        float4 q0 = p[0], q1 = p[1], q2 = p[2], q3 = p[3];
        a[0]=q0.x; a[1]=q0.y; a[2]=q0.z; a[3]=q0.w;
        a[4]=q1.x; a[5]=q1.y; a[6]=q1.z; a[7]=q1.w;
        a[8]=q2.x; a[9]=q2.y; a[10]=q2.z; a[11]=q2.w;
        a[12]=q3.x; a[13]=q3.y; a[14]=q3.z; a[15]=q3.w;
    } else {
#pragma unroll
        for (int k = 0; k < 16; ++k) a[k] = 0.0f;
    }
#pragma unroll
    for (int k = 0; k < 16; ++k) {
        float v = a[k];
        v += __shfl_down(v, 32);
        v += __shfl_down(v, 16);
        v += __shfl_down(v, 8);
        v += __shfl_down(v, 4);
        v += __shfl_down(v, 2);
        v += __shfl_down(v, 1);
        a[k] = v;                   // valid on lane 0 only
    }
    if (l != 0) return;

    float W = a[0];
    float A[3]  = {a[1], a[2], a[3]};
    float Bv[3] = {a[4], a[5], a[6]};
    float H[3][3];
#pragma unroll
    for (int i = 0; i < 3; ++i)
#pragma unroll
        for (int j = 0; j < 3; ++j)
            H[i][j] = a[7 + i*3 + j] + (W - 2.0f) * A[i] * Bv[j];

    // scale-normalize H (R is scale-invariant)
    float fn = 0.0f;
    for (int i = 0; i < 3; ++i) for (int j = 0; j < 3; ++j) fn += H[i][j]*H[i][j];
    fn = sqrtf(fn);
    float inv = (fn > 1e-30f) ? 1.0f/fn : 1.0f;
    float h[3][3];
    for (int i = 0; i < 3; ++i) for (int j = 0; j < 3; ++j) h[i][j] = H[i][j]*inv;

    // M = h^T h
    float M[3][3];
    for (int i = 0; i < 3; ++i)
        for (int j = 0; j < 3; ++j) {
            float s = 0.0f;
            for (int k = 0; k < 3; ++k) s += h[k][i] * h[k][j];
            M[i][j] = s;
        }

    // cyclic Jacobi: M = V diag(e) V^T
    float V[3][3] = {{1,0,0},{0,1,0},{0,0,1}};
    const int PAIRS[3][2] = {{0,1},{0,2},{1,2}};
    for (int sweep = 0; sweep < 12; ++sweep) {
        float off = M[0][1]*M[0][1] + M[0][2]*M[0][2] + M[1][2]*M[1][2];
        if (off < 1e-14f) break;
        for (int pp = 0; pp < 3; ++pp) {
            const int pq = PAIRS[pp][0], qq = PAIRS[pp][1];
            float apq = M[pq][qq];
            if (fabsf(apq) < 1e-30f) continue;
            float tau = (M[qq][qq] - M[pq][pq]) / (2.0f * apq);
            float t = (tau >= 0.0f ? 1.0f : -1.0f) / (fabsf(tau) + sqrtf(1.0f + tau*tau));
            float c = 1.0f / sqrtf(1.0f + t*t), s = t * c;
            for (int k = 0; k < 3; ++k) {
                float mkp = M[k][pq], mkq = M[k][qq];
                M[k][pq] = c*mkp - s*mkq;
                M[k][qq] = s*mkp + c*mkq;
            }
            for (int k = 0; k < 3; ++k) {
                float mpk = M[pq][k], mqk = M[qq][k];
                M[pq][k] = c*mpk - s*mqk;
                M[qq][k] = s*mpk + c*mqk;
            }
            for (int k = 0; k < 3; ++k) {
                float vkp = V[k][pq], vkq = V[k][qq];
                V[k][pq] = c*vkp - s*vkq;
                V[k][qq] = s*vkp + c*vkq;
            }
        }
    }

    // sort eigenvalues descending -> permute V columns
    float e[3] = {M[0][0], M[1][1], M[2][2]};
    int idx[3] = {0, 1, 2};
    if (e[idx[0]] < e[idx[1]]) { int t_ = idx[0]; idx[0] = idx[1]; idx[1] = t_; }
    if (e[idx[0]] < e[idx[2]]) { int t_ = idx[0]; idx[0] = idx[2]; idx[2] = t_; }
    if (e[idx[1]] < e[idx[2]]) { int t_ = idx[1]; idx[1] = idx[2]; idx[2] = t_; }
    float Vc[3][3];
    for (int i = 0; i < 3; ++i)
        for (int k = 0; k < 3; ++k) Vc[i][k] = V[i][idx[k]];

    // left singular vectors: u_k = h*v_k / |h*v_k|; u3 = u1 x u2
    float u[3][3], hv[3][3];
    for (int k = 0; k < 3; ++k)
        for (int j = 0; j < 3; ++j) {
            float s = 0.0f;
            for (int m = 0; m < 3; ++m) s += h[j][m] * Vc[m][k];
            hv[k][j] = s;
        }
    float n1 = sqrtf(hv[0][0]*hv[0][0] + hv[0][1]*hv[0][1] + hv[0][2]*hv[0][2]);
    float in1 = (n1 > 1e-20f) ? 1.0f/n1 : 0.0f;
    for (int j = 0; j < 3; ++j) u[0][j] = hv[0][j] * in1;
    if (in1 == 0.0f) { u[0][0] = 1.0f; u[0][1] = 0.0f; u[0][2] = 0.0f; }
    float d12 = u[0][0]*hv[1][0] + u[0][1]*hv[1][1] + u[0][2]*hv[1][2];
    float w2[3];
    for (int j = 0; j < 3; ++j) w2[j] = hv[1][j] - d12 * u[0][j];
    float n2 = sqrtf(w2[0]*w2[0] + w2[1]*w2[1] + w2[2]*w2[2]);
    if (n2 > 1e-20f) {
        for (int j = 0; j < 3; ++j) u[1][j] = w2[j] / n2;
    } else {
        float ax = fabsf(u[0][0]), ay = fabsf(u[0][1]), az = fabsf(u[0][2]);
        float t2[3];
        if (ax <= ay && ax <= az)      { t2[0]=0; t2[1]=-u[0][2]; t2[2]=u[0][1]; }
        else if (ay <= az)             { t2[0]=-u[0][2]; t2[1]=0; t2[2]=u[0][0]; }
        else                           { t2[0]=-u[0][1]; t2[1]=u[0][0]; t2[2]=0; }
        float nt = sqrtf(t2[0]*t2[0] + t2[1]*t2[1] + t2[2]*t2[2]);
        for (int j = 0; j < 3; ++j) u[1][j] = t2[j] / nt;
    }
    u[2][0] = u[0][1]*u[1][2] - u[0][2]*u[1][1];
    u[2][1] = u[0][2]*u[1][0] - u[0][0]*u[1][2];
    u[2][2] = u[0][0]*u[1][1] - u[0][1]*u[1][0];

    // R0 = V U^T; det fix flips V's 3rd column
    float R[3][3];
    for (int i = 0; i < 3; ++i)
        for (int j = 0; j < 3; ++j) {
            float s = 0.0f;
            for (int k = 0; k < 3; ++k) s += Vc[i][k] * u[k][j];
            R[i][j] = s;
        }
    float det = R[0][0]*(R[1][1]*R[2][2] - R[1][2]*R[2][1])
              - R[0][1]*(R[1][0]*R[2][2] - R[1][2]*R[2][0])
              + R[0][2]*(R[1][0]*R[2][1] - R[1][1]*R[2][0]);
    if (det < 0.0f)
        for (int i = 0; i < 3; ++i)
            for (int j = 0; j < 3; ++j)
                R[i][j] -= 2.0f * Vc[i][2] * u[2][j];

    float tv[3];
    for (int i = 0; i < 3; ++i)
        tv[i] = Bv[i] - (R[i][0]*A[0] + R[i][1]*A[1] + R[i][2]*A[2]);

    for (int i = 0; i < 3; ++i)
        for (int j = 0; j < 3; ++j)
            out[b*9 + i*3 + j] = R[i][j];
    for (int i = 0; i < 3; ++i)
        out[B_BATCH*9 + b*3 + i] = tv[i];
}

// ---------------------------------------------------------------------------
extern "C" void kernel_launch(void* const* d_in, const int* in_sizes, int n_in,
                              void* d_out, int out_size, void* d_ws, size_t ws_size,
                              hipStream_t stream) {
    const float* src = (const float*)d_in[0];
    const float* tgt = (const float*)d_in[1];
    const float* w   = (const float*)d_in[2];
    float* out  = (float*)d_out;
    float* part = (float*)d_ws;     // 64*16*16 floats = 64 KB

    partial_sums<<<B_BATCH * BPB, THREADS, 0, stream>>>(src, tgt, w, part);
    finalize<<<B_BATCH, 64, 0, stream>>>(part, out);
}

// Round 5
// 143.456 us; speedup vs baseline: 1.0555x; 1.0332x over previous
//
#include <hip/hip_runtime.h>
#include <math.h>

#define B_BATCH 64
#define N_PTS   65536
#define BPB     64                  // blocks per batch -> 4096 WGs
#define THREADS 256
#define CHUNK   (N_PTS / BPB)       // 1024 points per block = 256 thr * 4

// native vector type: __builtin_nontemporal_load requires scalar/vector of
// scalar, not HIP's struct float4
typedef float floatx4 __attribute__((ext_vector_type(4)));

// ---------------------------------------------------------------------------
// Kernel 1: per-batch 16 weighted sums, one float4 per stream per thread
// (R2 structure), plus:
//  - nontemporal loads (streaming; no cache allocate) on all 7 streams
//  - XCD-aware swizzle: blocks on XCD x (dispatch round-robin blockIdx%8)
//    cover batches [x*8, x*8+8) -> contiguous ~14 MB region per XCD
//   part[(b*BPB+blk)*16 + k]: 0=sum w, 1..3=sum w*s, 4..6=sum w*t,
//                             7..15=sum w*s_i*t_j (row-major)
// ---------------------------------------------------------------------------
__global__ __launch_bounds__(THREADS) void partial_sums(
        const float* __restrict__ src, const float* __restrict__ tgt,
        const float* __restrict__ w,  float* __restrict__ part) {
    // swizzle: xcd = blockIdx%8 owns batches xcd*8 .. xcd*8+7
    const int xcd   = blockIdx.x & 7;
    const int local = blockIdx.x >> 3;          // 0..511
    const int b     = xcd * 8 + (local & 7);    // batch
    const int blk   = local >> 3;               // 0..63 chunk within batch
    const int n0    = blk * CHUNK;
    const int t     = threadIdx.x;

    const floatx4* wp = (const floatx4*)(w   + (size_t)b * N_PTS          + n0);
    const floatx4* s0 = (const floatx4*)(src + ((size_t)b*3 + 0) * N_PTS + n0);
    const floatx4* s1 = (const floatx4*)(src + ((size_t)b*3 + 1) * N_PTS + n0);
    const floatx4* s2 = (const floatx4*)(src + ((size_t)b*3 + 2) * N_PTS + n0);
    const floatx4* t0 = (const floatx4*)(tgt + ((size_t)b*3 + 0) * N_PTS + n0);
    const floatx4* t1 = (const floatx4*)(tgt + ((size_t)b*3 + 1) * N_PTS + n0);
    const floatx4* t2 = (const floatx4*)(tgt + ((size_t)b*3 + 2) * N_PTS + n0);

    // 7 independent nontemporal 16B loads
    floatx4 wv = __builtin_nontemporal_load(&wp[t]);
    floatx4 x0 = __builtin_nontemporal_load(&s0[t]);
    floatx4 x1 = __builtin_nontemporal_load(&s1[t]);
    floatx4 x2 = __builtin_nontemporal_load(&s2[t]);
    floatx4 y0 = __builtin_nontemporal_load(&t0[t]);
    floatx4 y1 = __builtin_nontemporal_load(&t1[t]);
    floatx4 y2 = __builtin_nontemporal_load(&t2[t]);

    float a[16];
#pragma unroll
    for (int k = 0; k < 16; ++k) a[k] = 0.0f;

#define ACC1(WW, X0, X1, X2, Y0, Y1, Y2) { \
    float ww = WW; \
    float ws0 = ww * X0, ws1 = ww * X1, ws2 = ww * X2; \
    a[0]  += ww; \
    a[1]  += ws0;       a[2]  += ws1;       a[3]  += ws2; \
    a[4]  += ww * Y0;   a[5]  += ww * Y1;   a[6]  += ww * Y2; \
    a[7]  += ws0 * Y0;  a[8]  += ws0 * Y1;  a[9]  += ws0 * Y2; \
    a[10] += ws1 * Y0;  a[11] += ws1 * Y1;  a[12] += ws1 * Y2; \
    a[13] += ws2 * Y0;  a[14] += ws2 * Y1;  a[15] += ws2 * Y2; }
#pragma unroll
    for (int c = 0; c < 4; ++c) {
        ACC1(wv[c], x0[c], x1[c], x2[c], y0[c], y1[c], y2[c])
    }
#undef ACC1

    // block reduction: wave64 shuffle tree, then LDS across the 4 waves
    const int lane = t & 63;
    const int wave = t >> 6;
    __shared__ float lds[4][16];
#pragma unroll
    for (int k = 0; k < 16; ++k) {
        float v = a[k];
        v += __shfl_down(v, 32);
        v += __shfl_down(v, 16);
        v += __shfl_down(v, 8);
        v += __shfl_down(v, 4);
        v += __shfl_down(v, 2);
        v += __shfl_down(v, 1);
        if (lane == 0) lds[wave][k] = v;
    }
    __syncthreads();
    if (t < 16) {
        float v = lds[0][t] + lds[1][t] + lds[2][t] + lds[3][t];
        part[(size_t)(b * BPB + blk) * 16 + t] = v;
    }
}

// ---------------------------------------------------------------------------
// Kernel 2: one block per batch. 64 lanes each load one partial (16 floats),
// shuffle-reduce across the wave, lane 0 runs fp32 Jacobi Kabsch.
// ---------------------------------------------------------------------------
__global__ __launch_bounds__(64) void finalize(
        const float* __restrict__ part, float* __restrict__ out) {
    const int b = blockIdx.x;
    const int l = threadIdx.x;      // 0..63

    const float4* p = (const float4*)(part + (size_t)(b * BPB + l) * 16);
    float4 q0 = p[0], q1 = p[1], q2 = p[2], q3 = p[3];
    float a[16] = {q0.x,q0.y,q0.z,q0.w, q1.x,q1.y,q1.z,q1.w,
                   q2.x,q2.y,q2.z,q2.w, q3.x,q3.y,q3.z,q3.w};
#pragma unroll
    for (int k = 0; k < 16; ++k) {
        float v = a[k];
        v += __shfl_down(v, 32);
        v += __shfl_down(v, 16);
        v += __shfl_down(v, 8);
        v += __shfl_down(v, 4);
        v += __shfl_down(v, 2);
        v += __shfl_down(v, 1);
        a[k] = v;                   // valid on lane 0 only
    }
    if (l != 0) return;

    float W = a[0];
    float A[3]  = {a[1], a[2], a[3]};
    float Bv[3] = {a[4], a[5], a[6]};
    float H[3][3];
#pragma unroll
    for (int i = 0; i < 3; ++i)
#pragma unroll
        for (int j = 0; j < 3; ++j)
            H[i][j] = a[7 + i*3 + j] + (W - 2.0f) * A[i] * Bv[j];

    // scale-normalize H (R is scale-invariant)
    float fn = 0.0f;
    for (int i = 0; i < 3; ++i) for (int j = 0; j < 3; ++j) fn += H[i][j]*H[i][j];
    fn = sqrtf(fn);
    float inv = (fn > 1e-30f) ? 1.0f/fn : 1.0f;
    float h[3][3];
    for (int i = 0; i < 3; ++i) for (int j = 0; j < 3; ++j) h[i][j] = H[i][j]*inv;

    // M = h^T h
    float M[3][3];
    for (int i = 0; i < 3; ++i)
        for (int j = 0; j < 3; ++j) {
            float s = 0.0f;
            for (int k = 0; k < 3; ++k) s += h[k][i] * h[k][j];
            M[i][j] = s;
        }

    // cyclic Jacobi: M = V diag(e) V^T
    float V[3][3] = {{1,0,0},{0,1,0},{0,0,1}};
    const int PAIRS[3][2] = {{0,1},{0,2},{1,2}};
    for (int sweep = 0; sweep < 12; ++sweep) {
        float off = M[0][1]*M[0][1] + M[0][2]*M[0][2] + M[1][2]*M[1][2];
        if (off < 1e-14f) break;
        for (int pp = 0; pp < 3; ++pp) {
            const int pq = PAIRS[pp][0], qq = PAIRS[pp][1];
            float apq = M[pq][qq];
            if (fabsf(apq) < 1e-30f) continue;
            float tau = (M[qq][qq] - M[pq][pq]) / (2.0f * apq);
            float t = (tau >= 0.0f ? 1.0f : -1.0f) / (fabsf(tau) + sqrtf(1.0f + tau*tau));
            float c = 1.0f / sqrtf(1.0f + t*t), s = t * c;
            for (int k = 0; k < 3; ++k) {
                float mkp = M[k][pq], mkq = M[k][qq];
                M[k][pq] = c*mkp - s*mkq;
                M[k][qq] = s*mkp + c*mkq;
            }
            for (int k = 0; k < 3; ++k) {
                float mpk = M[pq][k], mqk = M[qq][k];
                M[pq][k] = c*mpk - s*mqk;
                M[qq][k] = s*mpk + c*mqk;
            }
            for (int k = 0; k < 3; ++k) {
                float vkp = V[k][pq], vkq = V[k][qq];
                V[k][pq] = c*vkp - s*vkq;
                V[k][qq] = s*vkp + c*vkq;
            }
        }
    }

    // sort eigenvalues descending -> permute V columns
    float e[3] = {M[0][0], M[1][1], M[2][2]};
    int idx[3] = {0, 1, 2};
    if (e[idx[0]] < e[idx[1]]) { int t_ = idx[0]; idx[0] = idx[1]; idx[1] = t_; }
    if (e[idx[0]] < e[idx[2]]) { int t_ = idx[0]; idx[0] = idx[2]; idx[2] = t_; }
    if (e[idx[1]] < e[idx[2]]) { int t_ = idx[1]; idx[1] = idx[2]; idx[2] = t_; }
    float Vc[3][3];
    for (int i = 0; i < 3; ++i)
        for (int k = 0; k < 3; ++k) Vc[i][k] = V[i][idx[k]];

    // left singular vectors: u_k = h*v_k / |h*v_k|; u3 = u1 x u2
    float u[3][3], hv[3][3];
    for (int k = 0; k < 3; ++k)
        for (int j = 0; j < 3; ++j) {
            float s = 0.0f;
            for (int m = 0; m < 3; ++m) s += h[j][m] * Vc[m][k];
            hv[k][j] = s;
        }
    float n1 = sqrtf(hv[0][0]*hv[0][0] + hv[0][1]*hv[0][1] + hv[0][2]*hv[0][2]);
    float in1 = (n1 > 1e-20f) ? 1.0f/n1 : 0.0f;
    for (int j = 0; j < 3; ++j) u[0][j] = hv[0][j] * in1;
    if (in1 == 0.0f) { u[0][0] = 1.0f; u[0][1] = 0.0f; u[0][2] = 0.0f; }
    float d12 = u[0][0]*hv[1][0] + u[0][1]*hv[1][1] + u[0][2]*hv[1][2];
    float w2[3];
    for (int j = 0; j < 3; ++j) w2[j] = hv[1][j] - d12 * u[0][j];
    float n2 = sqrtf(w2[0]*w2[0] + w2[1]*w2[1] + w2[2]*w2[2]);
    if (n2 > 1e-20f) {
        for (int j = 0; j < 3; ++j) u[1][j] = w2[j] / n2;
    } else {
        float ax = fabsf(u[0][0]), ay = fabsf(u[0][1]), az = fabsf(u[0][2]);
        float t2[3];
        if (ax <= ay && ax <= az)      { t2[0]=0; t2[1]=-u[0][2]; t2[2]=u[0][1]; }
        else if (ay <= az)             { t2[0]=-u[0][2]; t2[1]=0; t2[2]=u[0][0]; }
        else                           { t2[0]=-u[0][1]; t2[1]=u[0][0]; t2[2]=0; }
        float nt = sqrtf(t2[0]*t2[0] + t2[1]*t2[1] + t2[2]*t2[2]);
        for (int j = 0; j < 3; ++j) u[1][j] = t2[j] / nt;
    }
    u[2][0] = u[0][1]*u[1][2] - u[0][2]*u[1][1];
    u[2][1] = u[0][2]*u[1][0] - u[0][0]*u[1][2];
    u[2][2] = u[0][0]*u[1][1] - u[0][1]*u[1][0];

    // R0 = V U^T; det fix flips V's 3rd column
    float R[3][3];
    for (int i = 0; i < 3; ++i)
        for (int j = 0; j < 3; ++j) {
            float s = 0.0f;
            for (int k = 0; k < 3; ++k) s += Vc[i][k] * u[k][j];
            R[i][j] = s;
        }
    float det = R[0][0]*(R[1][1]*R[2][2] - R[1][2]*R[2][1])
              - R[0][1]*(R[1][0]*R[2][2] - R[1][2]*R[2][0])
              + R[0][2]*(R[1][0]*R[2][1] - R[1][1]*R[2][0]);
    if (det < 0.0f)
        for (int i = 0; i < 3; ++i)
            for (int j = 0; j < 3; ++j)
                R[i][j] -= 2.0f * Vc[i][2] * u[2][j];

    float tv[3];
    for (int i = 0; i < 3; ++i)
        tv[i] = Bv[i] - (R[i][0]*A[0] + R[i][1]*A[1] + R[i][2]*A[2]);

    for (int i = 0; i < 3; ++i)
        for (int j = 0; j < 3; ++j)
            out[b*9 + i*3 + j] = R[i][j];
    for (int i = 0; i < 3; ++i)
        out[B_BATCH*9 + b*3 + i] = tv[i];
}

// ---------------------------------------------------------------------------
extern "C" void kernel_launch(void* const* d_in, const int* in_sizes, int n_in,
                              void* d_out, int out_size, void* d_ws, size_t ws_size,
                              hipStream_t stream) {
    const float* src = (const float*)d_in[0];
    const float* tgt = (const float*)d_in[1];
    const float* w   = (const float*)d_in[2];
    float* out  = (float*)d_out;
    float* part = (float*)d_ws;     // 64*64*16 floats = 256 KB

    partial_sums<<<B_BATCH * BPB, THREADS, 0, stream>>>(src, tgt, w, part);
    finalize<<<B_BATCH, 64, 0, stream>>>(part, out);
}